// Round 1
// baseline (815.994 us; speedup 1.0000x reference)
//
#include <hip/hip_runtime.h>
#include <hip/hip_bf16.h>

// Problem constants (from reference setup_inputs)
constexpr int B = 16;
constexpr int C = 19;
constexpr int H = 512;
constexpr int W = 1024;
constexpr int HW = H * W;               // 524288 = 2^19
constexpr int HW_SHIFT = 19;            // log2(HW)
constexpr int N = B * HW;               // 8388608 pixels
constexpr int NVEC = N / 4;             // float4-pixels
constexpr int CM_BINS = C * C;          // 361
constexpr float SMOOTH = 1e-6f;
constexpr float WEIGHT = 0.5f;

// Kernel 1: per-pixel argmax over classes + LDS confusion-matrix histogram,
// flushed to global with atomics.
__global__ void __launch_bounds__(256)
hist_kernel(const float* __restrict__ logits,
            const int* __restrict__ target,
            unsigned int* __restrict__ cm) {
    __shared__ unsigned int lcm[CM_BINS];
    for (int i = threadIdx.x; i < CM_BINS; i += blockDim.x) lcm[i] = 0;
    __syncthreads();

    const int stride = gridDim.x * blockDim.x;
    for (int j = blockIdx.x * blockDim.x + threadIdx.x; j < NVEC; j += stride) {
        const int p  = j << 2;                 // base scalar pixel index
        const int b  = p >> HW_SHIFT;          // image index
        const int hw = p & (HW - 1);           // offset within image (mult of 4)
        const float* p0 = logits + b * (C * HW) + hw;

        float4 v = *reinterpret_cast<const float4*>(p0);
        float bvx = v.x, bvy = v.y, bvz = v.z, bvw = v.w;
        int   bix = 0,   biy = 0,   biz = 0,   biw = 0;
#pragma unroll
        for (int c = 1; c < C; c++) {
            v = *reinterpret_cast<const float4*>(p0 + c * HW);
            if (v.x > bvx) { bvx = v.x; bix = c; }
            if (v.y > bvy) { bvy = v.y; biy = c; }
            if (v.z > bvz) { bvz = v.z; biz = c; }
            if (v.w > bvw) { bvw = v.w; biw = c; }
        }

        const int4 t = *reinterpret_cast<const int4*>(target + p);
        atomicAdd(&lcm[t.x * C + bix], 1u);
        atomicAdd(&lcm[t.y * C + biy], 1u);
        atomicAdd(&lcm[t.z * C + biz], 1u);
        atomicAdd(&lcm[t.w * C + biw], 1u);
    }

    __syncthreads();
    for (int i = threadIdx.x; i < CM_BINS; i += blockDim.x) {
        unsigned int cnt = lcm[i];
        if (cnt) atomicAdd(&cm[i], cnt);
    }
}

// Kernel 2: tiny epilogue — sens/spec/loss from the 19x19 confusion matrix.
__global__ void __launch_bounds__(64)
finalize_kernel(const unsigned int* __restrict__ cm, float* __restrict__ out) {
    __shared__ float s_row[C], s_col[C], s_tp[C];
    const int c = threadIdx.x;
    if (c < C) {
        float rs = 0.f, cs = 0.f;
        for (int k = 0; k < C; k++) {
            rs += (float)cm[c * C + k];   // row = y_true (sum_along_classified)
            cs += (float)cm[k * C + c];   // col = y_pred (sum_along_actual)
        }
        s_row[c] = rs;
        s_col[c] = cs;
        s_tp[c]  = (float)cm[c * C + c];
    }
    __syncthreads();
    if (threadIdx.x == 0) {
        float total = 0.f;
        for (int k = 0; k < C; k++) total += s_row[k];
        float acc = 0.f;
        for (int k = 0; k < C; k++) {
            const float tp = s_tp[k];
            const float fp = s_row[k] - tp;
            const float fn = s_col[k] - tp;
            const float tn = total - tp - fp - fn;
            const float sens = (tp + SMOOTH) / (tp + fn + SMOOTH);
            const float spec = (tn + SMOOTH) / (tn + fp + SMOOTH);
            acc += WEIGHT * sens + (1.0f - WEIGHT) * spec;
        }
        out[0] = 1.0f - acc / (float)C;
    }
}

extern "C" void kernel_launch(void* const* d_in, const int* in_sizes, int n_in,
                              void* d_out, int out_size, void* d_ws, size_t ws_size,
                              hipStream_t stream) {
    const float* logits = (const float*)d_in[0];
    const int*   target = (const int*)d_in[1];
    float*       out    = (float*)d_out;
    unsigned int* cm    = (unsigned int*)d_ws;

    // d_ws is poisoned 0xAA before every launch — zero the confusion matrix.
    hipMemsetAsync(cm, 0, CM_BINS * sizeof(unsigned int), stream);

    hist_kernel<<<1024, 256, 0, stream>>>(logits, target, cm);
    finalize_kernel<<<1, 64, 0, stream>>>(cm, out);
}